// Round 21
// baseline (1356.352 us; speedup 1.0000x reference)
//
#include <hip/hip_runtime.h>

#define B_  64
#define T_  512
#define D_  64
#define U_  256
#define G4  1024   // 4*U
#define NT  1024   // 16 waves, 4 per SIMD (TLP to hide L2 stream latency)
#define NLDS2 9    // LDS frags/wave: kt0 q0-3, kt1 q0-3, kt2 q0 (stream = 23)

typedef _Float16 f16x8 __attribute__((ext_vector_type(8)));   // 16 B = 4 regs
typedef float    f32x4 __attribute__((ext_vector_type(4)));

__device__ __forceinline__ float sigmoidf_(float z) {
    return 1.f / (1.f + __expf(-z));
}

// B frag element: lane (gg, li), elem e -> U[32*kt + 8*gg + e][16*ntg + li]
__device__ __forceinline__ f16x8 load_bfrag(const float* __restrict__ Um,
                                            int ntg, int kt, int gg, int li) {
    const float* p = Um + (size_t)(32 * kt + 8 * gg) * G4 + 16 * ntg + li;
    f16x8 v;
    #pragma unroll
    for (int e = 0; e < 8; ++e) v[e] = (_Float16)p[(size_t)e * G4];
    return v;
}

// 16-wave column map: wave W (0..15), local tile Q (0..3) -> 16-col tile 16Q+W
#define NTG16(W, Q) (16 * (Q) + (W))

// ---------------------------------------------------------------------------
// Kernel 1: xz[t*B+b][g] = bias[g] + sum_d x[b][t][d] * W[d][g]   (fp32 exact)
// ---------------------------------------------------------------------------
__global__ __launch_bounds__(256) void xz_kernel(const float* __restrict__ x,
                                                 const float* __restrict__ W,
                                                 const float* __restrict__ bias,
                                                 float* __restrict__ xz) {
    __shared__ float xt[16][D_];
    const int g    = blockIdx.x * 256 + threadIdx.x;
    const int row0 = blockIdx.y * 16;

    #pragma unroll
    for (int j = 0; j < 4; ++j) {
        int e = threadIdx.x + 256 * j;
        int r = e >> 6, d = e & 63;
        int row = row0 + r;
        int t = row >> 6, bb = row & 63;        // row = t*64 + b
        xt[r][d] = x[((size_t)bb * T_ + t) * D_ + d];
    }
    __syncthreads();

    float acc[16];
    #pragma unroll
    for (int r = 0; r < 16; ++r) acc[r] = 0.f;

    for (int d = 0; d < D_; ++d) {
        float wv = W[(size_t)d * G4 + g];
        #pragma unroll
        for (int r = 0; r < 16; ++r) acc[r] += xt[r][d] * wv;
    }

    float bg = bias[g];
    #pragma unroll
    for (int r = 0; r < 16; ++r)
        xz[(size_t)(row0 + r) * G4 + g] = acc[r] + bg;
}

// ---------------------------------------------------------------------------
// Kernel 1b: pack U for the 16-wave map.
// pk[((w*8+kt)*4+q)*64 + lane] = frag(NTG16(w,q), kt, gg(lane), li(lane)).
// 512 frags x 64 lanes x 16 B = 512 KiB, identical for all WGs -> L2-shared.
// ---------------------------------------------------------------------------
__global__ __launch_bounds__(256) void pack_kernel(const float* __restrict__ Um,
                                                   f16x8* __restrict__ pk) {
    const int idx  = blockIdx.x * 256 + threadIdx.x;   // 0 .. 32767
    const int lane = idx & 63;
    const int fid  = idx >> 6;         // w*32 + kt*4 + q
    const int q    = fid & 3;
    const int kt   = (fid >> 2) & 7;
    const int w    = fid >> 5;
    const int gg   = (lane >> 4) & 3;
    const int li   = lane & 15;
    pk[idx] = load_bfrag(Um, NTG16(w, q), kt, gg, li);
}

// ---------------------------------------------------------------------------
// Kernel 2 (primary): MFMA LSTM scan, 16 waves (4/SIMD), wave-local gates,
// ONE barrier/step. Wave w owns cols {256q + 16w + li, q=0..3}: 4 N-tiles x
// 8 kt = 32 frags (9 LDS + 23 streamed). Same per-CU supply as round 20 but
// 2x the wave contexts to hide L2 latency (round-19/20 showed the stream is
// latency-critical at 2 waves/SIMD). Unit u = 16w+li's four gates land in
// acc0..acc3[0] on lanes<16 -> no z LDS round-trip, one barrier.
// A = h broadcast to all 16 rows; A,B share the (k-group,elem)->k pattern.
// ---------------------------------------------------------------------------

struct Smem16 {
    _Float16 h16[2][256];       // 1 KB  (double-buffered h)
    float    pd[2][U_];         // 2 KB  (double-buffered dense partials)
    f16x8    bl[16][NLDS2][64]; // 144 KB LDS-resident B frags
};                              // 150528 B (>82 KB -> 1 WG/CU)

#define MMV(N, BV) acc##N = __builtin_amdgcn_mfma_f32_16x16x32_f16(av, (BV), acc##N, 0, 0, 0);
#define MMS(K, Q)  { f16x8 bv = pkp[(((K) << 2) | (Q)) << 6]; \
                     acc##Q = __builtin_amdgcn_mfma_f32_16x16x32_f16(av, bv, acc##Q, 0, 0, 0); }

#define MKSTRM4(KT) { \
    f16x8 av = *(const f16x8*)&hp[32 * (KT) + 8 * gg]; \
    MMS(KT,0) MMS(KT,1) MMS(KT,2) MMS(KT,3) }

__global__
__attribute__((amdgpu_flat_work_group_size(NT, NT), amdgpu_waves_per_eu(4, 4)))
void lstm_kernel(
        const float* __restrict__ Um,
        const float* __restrict__ dw,
        const float* __restrict__ dbp,
        const float* __restrict__ xz,
        const f16x8* __restrict__ pk,
        float* __restrict__ out) {
    __shared__ Smem16 sm;

    const int tau  = threadIdx.x;
    const int b    = blockIdx.x;
    const int w    = tau >> 6;          // wave 0..15
    const int lane = tau & 63;
    const int gg   = (tau >> 4) & 3;    // 16-lane k-group
    const int li   = tau & 15;
    const int u    = 16 * w + li;       // unit owned (lanes>=16 duplicate)

    // per-thread base into the shared packed frag buffer (w*2048 frag-slots)
    const f16x8* __restrict__ pkp = pk + ((size_t)w << 11) + lane;

    // ---- one-time: LDS B frags. f0..3 kt0 q0..3; f4..7 kt1 q0..3; f8 kt2 q0
    #pragma unroll
    for (int f = 0; f < NLDS2; ++f) {
        const int kt = (f < 4) ? 0 : (f < 8) ? 1 : 2;
        const int q  = (f < 8) ? (f & 3) : 0;
        sm.bl[w][f][lane] = load_bfrag(Um, NTG16(w, q), kt, gg, li);
    }

    if (tau < U_) sm.h16[0][tau] = (_Float16)0.f;

    const float dwr = (lane < 16) ? dw[u] : 0.f;
    const float db0 = dbp[0];
    float c_state = 0.f;

    __syncthreads();

    for (int t = 0; t < T_; ++t) {
        const int cur = t & 1, nxt = cur ^ 1;

        // ---- dense for step t-1 (pd[(t-1)&1] sealed by last barrier);
        //      tau<64 only, overlaps the other waves' MFMA phase.
        if (t > 0 && tau < 64) {
            const float* pp = sm.pd[nxt];   // (t-1)&1 == nxt
            float s = pp[tau] + pp[tau + 64] + pp[tau + 128] + pp[tau + 192];
            #pragma unroll
            for (int off = 32; off > 0; off >>= 1)
                s += __shfl_down(s, off);
            if (tau == 0) out[(size_t)b * T_ + (t - 1)] = s + db0;
        }

        // ---- issue xz[t] for this step's gates (lanes<16; consumed at the
        //      end of the MFMA phase -> latency hidden).
        float xq0 = 0.f, xq1 = 0.f, xq2 = 0.f, xq3 = 0.f;
        if (lane < 16) {
            const float* xp = xz + ((size_t)t * B_ + b) * G4;
            xq0 = xp[u];
            xq1 = xp[256 + u];
            xq2 = xp[512 + u];
            xq3 = xp[768 + u];
        }
        __builtin_amdgcn_sched_barrier(0);   // keep load issue above the MFMAs

        // ---- MFMA phase: this wave's 4 col-tiles x K=256 (32 frags) ----
        const _Float16* hp = &sm.h16[cur][0];
        f32x4 acc0 = {0.f,0.f,0.f,0.f}, acc1 = {0.f,0.f,0.f,0.f};
        f32x4 acc2 = {0.f,0.f,0.f,0.f}, acc3 = {0.f,0.f,0.f,0.f};

        {   // kt=0: q0..3 from LDS
            f16x8 av = *(const f16x8*)&hp[8 * gg];
            { f16x8 bv = sm.bl[w][0][lane]; MMV(0, bv) }
            { f16x8 bv = sm.bl[w][1][lane]; MMV(1, bv) }
            { f16x8 bv = sm.bl[w][2][lane]; MMV(2, bv) }
            { f16x8 bv = sm.bl[w][3][lane]; MMV(3, bv) }
        }
        {   // kt=1: q0..3 from LDS
            f16x8 av = *(const f16x8*)&hp[32 + 8 * gg];
            { f16x8 bv = sm.bl[w][4][lane]; MMV(0, bv) }
            { f16x8 bv = sm.bl[w][5][lane]; MMV(1, bv) }
            { f16x8 bv = sm.bl[w][6][lane]; MMV(2, bv) }
            { f16x8 bv = sm.bl[w][7][lane]; MMV(3, bv) }
        }
        {   // kt=2: q0 LDS, q1..3 streamed
            f16x8 av = *(const f16x8*)&hp[64 + 8 * gg];
            { f16x8 bv = sm.bl[w][8][lane]; MMV(0, bv) }
            MMS(2,1) MMS(2,2) MMS(2,3)
        }
        MKSTRM4(3) MKSTRM4(4) MKSTRM4(5) MKSTRM4(6) MKSTRM4(7)

        // ---- wave-local gates: unit u's 4 gates are acc0..acc3[0] ----
        // (A rows identical -> every acc element equals the row value)
        if (lane < 16) {
            float zi = acc0[0] + xq0;
            float zf = acc1[0] + xq1;
            float zg = acc2[0] + xq2;
            float zo = acc3[0] + xq3;
            float ig = sigmoidf_(zi);
            float fg = sigmoidf_(zf);
            float gv = fmaxf(zg, 0.f);
            float og = sigmoidf_(zo);
            c_state = fg * c_state + ig * gv;
            float h = og * fmaxf(c_state, 0.f);
            sm.h16[nxt][u] = (_Float16)h;
            sm.pd[cur][u]  = h * dwr;
        }
        __syncthreads();                 // the ONE barrier: h[nxt], pd[cur] sealed
    }

    // ---- epilogue: out[T-1] ----
    if (tau < 64) {
        const float* pp = sm.pd[(T_ - 1) & 1];
        float s = pp[tau] + pp[tau + 64] + pp[tau + 128] + pp[tau + 192];
        #pragma unroll
        for (int off = 32; off > 0; off >>= 1)
            s += __shfl_down(s, off);
        if (tau == 0) out[(size_t)b * T_ + (T_ - 1)] = s + db0;
    }
}

// ---------------------------------------------------------------------------
// Kernel 2 (secondary, r15-proven): used when ws lacks the +512 KiB slack.
// ---------------------------------------------------------------------------
struct Smem15 {
    _Float16 h16[256];
    float    z[G4];
    float    pd[U_];
    f16x8    bl[8][17][64];
};

#define FOR_AG(X) \
    X(2,1) X(2,2) X(2,3) X(2,4) X(2,5) X(2,6) X(2,7) \
    X(3,0) X(3,1) X(3,2) X(3,3) X(3,4) X(3,5) X(3,6) X(3,7) \
    X(4,0) X(4,1) X(4,2) X(4,3) X(4,4) X(4,5) X(4,6) X(4,7) \
    X(5,0) X(5,1) X(5,2) X(5,3) X(5,4) X(5,5) X(5,6) X(5,7) \
    X(6,0) X(6,1) X(6,2) X(6,3) X(6,4) X(6,5) X(6,6) X(6,7) \
    X(7,0) X(7,1) X(7,2) X(7,3) X(7,4) X(7,5) X(7,6) X(7,7)

#define DB(K,N) f16x8 bF_##K##_##N;
#define IB(K,N) bF_##K##_##N = load_bfrag(Um, w8 + (N), (K), gg, li);
#define MMR(K, N)  acc##N = __builtin_amdgcn_mfma_f32_16x16x32_f16(av, bF_##K##_##N, acc##N, 0, 0, 0);
#define MKLDS15(KT, FB) { \
    f16x8 av = *(const f16x8*)&sm.h16[32 * (KT) + 8 * gg]; \
    { f16x8 bv = sm.bl[w][(FB)+0][lane]; MMV(0, bv) } \
    { f16x8 bv = sm.bl[w][(FB)+1][lane]; MMV(1, bv) } \
    { f16x8 bv = sm.bl[w][(FB)+2][lane]; MMV(2, bv) } \
    { f16x8 bv = sm.bl[w][(FB)+3][lane]; MMV(3, bv) } \
    { f16x8 bv = sm.bl[w][(FB)+4][lane]; MMV(4, bv) } \
    { f16x8 bv = sm.bl[w][(FB)+5][lane]; MMV(5, bv) } \
    { f16x8 bv = sm.bl[w][(FB)+6][lane]; MMV(6, bv) } \
    { f16x8 bv = sm.bl[w][(FB)+7][lane]; MMV(7, bv) } }
#define MKREG(KT) { \
    f16x8 av = *(const f16x8*)&sm.h16[32 * (KT) + 8 * gg]; \
    MMR(KT,0) MMR(KT,1) MMR(KT,2) MMR(KT,3) \
    MMR(KT,4) MMR(KT,5) MMR(KT,6) MMR(KT,7) }

__global__
__attribute__((amdgpu_flat_work_group_size(512, 512), amdgpu_waves_per_eu(2, 2)))
void lstm_kernel_r15(
        const float* __restrict__ Um,
        const float* __restrict__ dw,
        const float* __restrict__ dbp,
        const float* __restrict__ xz,
        float* __restrict__ out) {
    __shared__ Smem15 sm;

    const int tau  = threadIdx.x;
    const int b    = blockIdx.x;
    const int w    = tau >> 6;
    const int lane = tau & 63;
    const int gg   = (tau >> 4) & 3;
    const int li   = tau & 15;
    const int w8   = 8 * w;

    FOR_AG(DB)
    FOR_AG(IB)
    __builtin_amdgcn_sched_barrier(0);

    #pragma unroll
    for (int f = 0; f < 17; ++f) {
        const int kt = f >> 3, nt = f & 7;
        sm.bl[w][f][lane] = load_bfrag(Um, w8 + nt, kt, gg, li);
    }

    if (tau < U_) sm.h16[tau] = (_Float16)0.f;

    const float dwr = (tau < U_) ? dw[tau] : 0.f;
    const float db0 = dbp[0];
    float c_state = 0.f;

    float xq0 = 0.f, xq1 = 0.f, xq2 = 0.f, xq3 = 0.f;
    if (tau < U_) {
        const float* xp = xz + (size_t)b * G4;
        xq0 = xp[tau]; xq1 = xp[U_ + tau]; xq2 = xp[2 * U_ + tau]; xq3 = xp[3 * U_ + tau];
    }
    __syncthreads();

    for (int t = 0; t < T_; ++t) {
        const int tn = (t + 1 < T_) ? t + 1 : t;
        float xn0 = 0.f, xn1 = 0.f, xn2 = 0.f, xn3 = 0.f;
        if (tau < U_) {
            const float* xp = xz + ((size_t)tn * B_ + b) * G4;
            xn0 = xp[tau]; xn1 = xp[U_ + tau]; xn2 = xp[2 * U_ + tau]; xn3 = xp[3 * U_ + tau];
        }
        __builtin_amdgcn_sched_barrier(0);

        f32x4 acc0 = {0.f,0.f,0.f,0.f}, acc1 = {0.f,0.f,0.f,0.f};
        f32x4 acc2 = {0.f,0.f,0.f,0.f}, acc3 = {0.f,0.f,0.f,0.f};
        f32x4 acc4 = {0.f,0.f,0.f,0.f}, acc5 = {0.f,0.f,0.f,0.f};
        f32x4 acc6 = {0.f,0.f,0.f,0.f}, acc7 = {0.f,0.f,0.f,0.f};

        MKLDS15(0, 0)
        MKLDS15(1, 8)
        {
            f16x8 av = *(const f16x8*)&sm.h16[64 + 8 * gg];
            { f16x8 bv = sm.bl[w][16][lane]; MMV(0, bv) }
            MMR(2,1) MMR(2,2) MMR(2,3) MMR(2,4) MMR(2,5) MMR(2,6) MMR(2,7)
        }
        MKREG(3) MKREG(4) MKREG(5) MKREG(6) MKREG(7)

        if (lane < 16) {
            const int zb = 128 * w + lane;
            sm.z[zb]       = acc0.x;  sm.z[zb + 16]  = acc1.x;
            sm.z[zb + 32]  = acc2.x;  sm.z[zb + 48]  = acc3.x;
            sm.z[zb + 64]  = acc4.x;  sm.z[zb + 80]  = acc5.x;
            sm.z[zb + 96]  = acc6.x;  sm.z[zb + 112] = acc7.x;
        }
        __syncthreads();

        if (tau < U_) {
            float zi = sm.z[tau]            + xq0;
            float zf = sm.z[U_ + tau]       + xq1;
            float zg = sm.z[2 * U_ + tau]   + xq2;
            float zo = sm.z[3 * U_ + tau]   + xq3;
            float ig = sigmoidf_(zi);
            float fg = sigmoidf_(zf);
            float gv = fmaxf(zg, 0.f);
            float og = sigmoidf_(zo);
            c_state = fg * c_state + ig * gv;
            float h = og * fmaxf(c_state, 0.f);
            sm.h16[tau] = (_Float16)h;
            sm.pd[tau]  = h * dwr;
        }
        __syncthreads();

        if (tau < 64) {
            float s = sm.pd[tau] + sm.pd[tau + 64] + sm.pd[tau + 128] + sm.pd[tau + 192];
            #pragma unroll
            for (int off = 32; off > 0; off >>= 1)
                s += __shfl_down(s, off);
            if (tau == 0) out[(size_t)b * T_ + t] = s + db0;
        }

        xq0 = xn0; xq1 = xn1; xq2 = xn2; xq3 = xn3;
    }
}

// ---------------------------------------------------------------------------
// Fallback (no workspace): streaming kernel, correctness only.
// ---------------------------------------------------------------------------
__global__ __launch_bounds__(1024) void lstm_fallback(
        const float* __restrict__ x,  const float* __restrict__ W,
        const float* __restrict__ Um, const float* __restrict__ bias,
        const float* __restrict__ dw, const float* __restrict__ dbp,
        float* __restrict__ out) {
    __shared__ float h_s[U_];
    __shared__ float z_s2[G4];
    __shared__ float pd_s2[U_];
    const int g = threadIdx.x;
    const int b = blockIdx.x;
    const float bg  = bias[g];
    const float dwr = (g < U_) ? dw[g] : 0.f;
    const float db0 = dbp[0];
    float c = 0.f;
    if (g < U_) h_s[g] = 0.f;
    __syncthreads();
    const float* Ucol = Um + g;
    for (int t = 0; t < T_; ++t) {
        float acc = bg;
        const float* xrow = x + ((size_t)b * T_ + t) * D_;
        for (int d = 0; d < D_; ++d) acc += xrow[d] * W[(size_t)d * G4 + g];
        for (int k = 0; k < U_; ++k) acc += h_s[k] * Ucol[(size_t)k * G4];
        z_s2[g] = acc;
        __syncthreads();
        if (g < U_) {
            float ig = sigmoidf_(z_s2[g]);
            float fg = sigmoidf_(z_s2[U_ + g]);
            float gg2 = fmaxf(z_s2[2 * U_ + g], 0.f);
            float og = sigmoidf_(z_s2[3 * U_ + g]);
            c = fg * c + ig * gg2;
            float h = og * fmaxf(c, 0.f);
            h_s[g] = h; pd_s2[g] = h * dwr;
        }
        __syncthreads();
        if (g < 64) {
            float s = pd_s2[g] + pd_s2[g + 64] + pd_s2[g + 128] + pd_s2[g + 192];
            #pragma unroll
            for (int off = 32; off > 0; off >>= 1) s += __shfl_down(s, off);
            if (g == 0) out[(size_t)b * T_ + t] = s + db0;
        }
        __syncthreads();
    }
}

// ---------------------------------------------------------------------------
extern "C" void kernel_launch(void* const* d_in, const int* in_sizes, int n_in,
                              void* d_out, int out_size, void* d_ws, size_t ws_size,
                              hipStream_t stream) {
    const float* x    = (const float*)d_in[0];
    const float* W    = (const float*)d_in[1];
    const float* Um   = (const float*)d_in[2];
    const float* bias = (const float*)d_in[3];
    const float* dw   = (const float*)d_in[4];
    const float* db   = (const float*)d_in[5];
    float* out = (float*)d_out;

    const size_t need_xz  = (size_t)T_ * B_ * G4 * sizeof(float);   // 128 MiB
    const size_t pk_bytes = (size_t)512 * 64 * 16;                  // 512 KiB

    if (ws_size >= need_xz + pk_bytes) {
        f16x8* pk = (f16x8*)d_ws;
        float* xz = (float*)((char*)d_ws + pk_bytes);
        dim3 gridX(G4 / 256, (T_ * B_) / 16);
        xz_kernel<<<gridX, 256, 0, stream>>>(x, W, bias, xz);
        pack_kernel<<<128, 256, 0, stream>>>(Um, pk);
        lstm_kernel<<<B_, NT, 0, stream>>>(Um, dw, db, xz, pk, out);
    } else if (ws_size >= need_xz) {
        float* xz = (float*)d_ws;
        dim3 gridX(G4 / 256, (T_ * B_) / 16);
        xz_kernel<<<gridX, 256, 0, stream>>>(x, W, bias, xz);
        lstm_kernel_r15<<<B_, 512, 0, stream>>>(Um, dw, db, xz, out);
    } else {
        lstm_fallback<<<B_, 1024, 0, stream>>>(x, W, Um, bias, dw, db, out);
    }
}

// Round 22
// 808.038 us; speedup vs baseline: 1.6786x; 1.6786x over previous
//
#include <hip/hip_runtime.h>

#define B_  64
#define T_  512
#define D_  64
#define U_  256
#define G4  1024   // 4*U
#define NT  512    // 8 waves, 2 per SIMD
#define NLDS 19    // LDS frags/wave: kt0 x8, kt1 x8, kt2 nl0-2  (stream = 45)

typedef _Float16 f16x8 __attribute__((ext_vector_type(8)));   // 16 B = 4 regs
typedef float    f32x4 __attribute__((ext_vector_type(4)));

__device__ __forceinline__ float sigmoidf_(float z) {
    return 1.f / (1.f + __expf(-z));
}

// B frag element: lane (gg, li), elem e -> U[32*kt + 8*gg + e][16*ntg + li]
__device__ __forceinline__ f16x8 load_bfrag(const float* __restrict__ Um,
                                            int ntg, int kt, int gg, int li) {
    const float* p = Um + (size_t)(32 * kt + 8 * gg) * G4 + 16 * ntg + li;
    f16x8 v;
    #pragma unroll
    for (int e = 0; e < 8; ++e) v[e] = (_Float16)p[(size_t)e * G4];
    return v;
}

// wave-local column map: wave W, local tile NL (= 2q+s) -> global 16-col tile
#define NTGW(W, NL) (16 * ((NL) >> 1) + 2 * (W) + ((NL) & 1))

// ---------------------------------------------------------------------------
// Kernel 1: xz[t*B+b][g] = bias[g] + sum_d x[b][t][d] * W[d][g]   (fp32 exact)
// ---------------------------------------------------------------------------
__global__ __launch_bounds__(256) void xz_kernel(const float* __restrict__ x,
                                                 const float* __restrict__ W,
                                                 const float* __restrict__ bias,
                                                 float* __restrict__ xz) {
    __shared__ float xt[16][D_];
    const int g    = blockIdx.x * 256 + threadIdx.x;
    const int row0 = blockIdx.y * 16;

    #pragma unroll
    for (int j = 0; j < 4; ++j) {
        int e = threadIdx.x + 256 * j;
        int r = e >> 6, d = e & 63;
        int row = row0 + r;
        int t = row >> 6, bb = row & 63;        // row = t*64 + b
        xt[r][d] = x[((size_t)bb * T_ + t) * D_ + d];
    }
    __syncthreads();

    float acc[16];
    #pragma unroll
    for (int r = 0; r < 16; ++r) acc[r] = 0.f;

    for (int d = 0; d < D_; ++d) {
        float wv = W[(size_t)d * G4 + g];
        #pragma unroll
        for (int r = 0; r < 16; ++r) acc[r] += xt[r][d] * wv;
    }

    float bg = bias[g];
    #pragma unroll
    for (int r = 0; r < 16; ++r)
        xz[(size_t)(row0 + r) * G4 + g] = acc[r] + bg;
}

// ---------------------------------------------------------------------------
// Kernel 1b: pack U into the shared streamed-frag buffer (wave-local map).
// pk[((w*8+kt)*8+nl)*64 + lane] = frag(NTGW(w,nl), kt, gg(lane), li(lane)).
// 512 KiB, identical for all WGs -> one L2 copy per XCD serves everyone.
// ---------------------------------------------------------------------------
__global__ __launch_bounds__(256) void pack_kernel(const float* __restrict__ Um,
                                                   f16x8* __restrict__ pk) {
    const int idx  = blockIdx.x * 256 + threadIdx.x;   // 0 .. 32767
    const int lane = idx & 63;
    const int fid  = idx >> 6;         // w*64 + kt*8 + nl
    const int nl   = fid & 7;
    const int kt   = (fid >> 3) & 7;
    const int w    = fid >> 6;
    const int gg   = (lane >> 4) & 3;
    const int li   = lane & 15;
    pk[idx] = load_bfrag(Um, NTGW(w, nl), kt, gg, li);
}

// ---------------------------------------------------------------------------
// Kernel 2 (primary): MFMA LSTM scan, wave-local gates, ONE barrier/step.
// Supply split 19 LDS + 45 streamed — the measured optimum of this family:
//   L=13 (r19): +45% — stream is the saturated/latency channel
//   L=19 @512thr (r20): 808 us  <- THIS
//   L=9 @1024thr (r21): +59% — TLP halves the VGPR load window (64 regs)
// Wave w owns global cols {256q + 32w + 16s + li}; unit u = 32w+16s+li's 4
// gates land in this thread's own acc(2q+sel)[0] -> no z LDS round-trip.
// A = h broadcast to all 16 rows; A,B share the same (k-group,elem)->k load
// pattern so the HW k-map cancels (round-9-verified).
// ---------------------------------------------------------------------------

struct SmemWL {
    _Float16 h16[2][256];       // 1 KB  (double-buffered h)
    float    pd[2][U_];         // 2 KB  (double-buffered dense partials)
    f16x8    bl[8][NLDS][64];   // 152 KB LDS-resident B frags
};                              // 158720 B (< 163840; 1 WG/CU preserved)

#define MMV(N, BV) acc##N = __builtin_amdgcn_mfma_f32_16x16x32_f16(av, (BV), acc##N, 0, 0, 0);
#define MMS(K, N)  { f16x8 bv = pkp[(((K) << 3) | (N)) << 6]; \
                     acc##N = __builtin_amdgcn_mfma_f32_16x16x32_f16(av, bv, acc##N, 0, 0, 0); }

#define MKLDS8(KT, FB) { \
    f16x8 av = *(const f16x8*)&hp[32 * (KT) + 8 * gg]; \
    { f16x8 bv = sm.bl[w][(FB)+0][lane]; MMV(0, bv) } \
    { f16x8 bv = sm.bl[w][(FB)+1][lane]; MMV(1, bv) } \
    { f16x8 bv = sm.bl[w][(FB)+2][lane]; MMV(2, bv) } \
    { f16x8 bv = sm.bl[w][(FB)+3][lane]; MMV(3, bv) } \
    { f16x8 bv = sm.bl[w][(FB)+4][lane]; MMV(4, bv) } \
    { f16x8 bv = sm.bl[w][(FB)+5][lane]; MMV(5, bv) } \
    { f16x8 bv = sm.bl[w][(FB)+6][lane]; MMV(6, bv) } \
    { f16x8 bv = sm.bl[w][(FB)+7][lane]; MMV(7, bv) } }

#define MKSTRM(KT) { \
    f16x8 av = *(const f16x8*)&hp[32 * (KT) + 8 * gg]; \
    MMS(KT,0) MMS(KT,1) MMS(KT,2) MMS(KT,3) \
    MMS(KT,4) MMS(KT,5) MMS(KT,6) MMS(KT,7) }

__global__
__attribute__((amdgpu_flat_work_group_size(NT, NT), amdgpu_waves_per_eu(2, 2)))
void lstm_kernel(
        const float* __restrict__ Um,
        const float* __restrict__ dw,
        const float* __restrict__ dbp,
        const float* __restrict__ xz,
        const f16x8* __restrict__ pk,
        float* __restrict__ out) {
    __shared__ SmemWL sm;

    const int tau  = threadIdx.x;
    const int b    = blockIdx.x;
    const int w    = tau >> 6;          // wave 0..7
    const int lane = tau & 63;
    const int gg   = (tau >> 4) & 3;    // 16-lane k-group
    const int li   = tau & 15;
    const int sel  = (lane >> 4) & 1;   // 16-col half within the 32-unit block
    const int u    = 32 * w + 16 * sel + li;   // unit owned (lanes>=32 duplicate)

    // per-thread base into the shared packed frag buffer
    const f16x8* __restrict__ pkp = pk + ((size_t)w << 12) + lane;  // w*4096 + lane

    // ---- one-time: LDS B frags. f 0..7 -> kt0 nl0..7; 8..15 -> kt1 nl0..7;
    //      16..18 -> kt2 nl0..2. (kt2 nl3..7, kt3..7 come from pk.)
    #pragma unroll
    for (int f = 0; f < NLDS; ++f) {
        const int kt = (f < 8) ? 0 : (f < 16) ? 1 : 2;
        const int nl = (f < 16) ? (f & 7) : (f - 16);
        sm.bl[w][f][lane] = load_bfrag(Um, NTGW(w, nl), kt, gg, li);
    }

    if (tau < U_) sm.h16[0][tau] = (_Float16)0.f;

    const float dwr = (lane < 32) ? dw[u] : 0.f;
    const float db0 = dbp[0];
    float c_state = 0.f;

    __syncthreads();

    for (int t = 0; t < T_; ++t) {
        const int cur = t & 1, nxt = cur ^ 1;

        // ---- dense for step t-1 (pd[(t-1)&1] sealed by last barrier);
        //      tau<64 only, overlaps the other waves' MFMA phase.
        if (t > 0 && tau < 64) {
            const float* pp = sm.pd[nxt];   // (t-1)&1 == nxt
            float s = pp[tau] + pp[tau + 64] + pp[tau + 128] + pp[tau + 192];
            #pragma unroll
            for (int off = 32; off > 0; off >>= 1)
                s += __shfl_down(s, off);
            if (tau == 0) out[(size_t)b * T_ + (t - 1)] = s + db0;
        }

        // ---- issue xz[t] for this step's gates (lanes<32; consumed ~2000
        //      cyc later). Oldest in the vmem queue -> drained first.
        float xq0 = 0.f, xq1 = 0.f, xq2 = 0.f, xq3 = 0.f;
        if (lane < 32) {
            const float* xp = xz + ((size_t)t * B_ + b) * G4;
            xq0 = xp[u];
            xq1 = xp[256 + u];
            xq2 = xp[512 + u];
            xq3 = xp[768 + u];
        }
        __builtin_amdgcn_sched_barrier(0);   // keep load issue above the MFMAs

        // ---- MFMA phase: this wave's 8 col-tiles x K=256 ----
        const _Float16* hp = &sm.h16[cur][0];
        f32x4 acc0 = {0.f,0.f,0.f,0.f}, acc1 = {0.f,0.f,0.f,0.f};
        f32x4 acc2 = {0.f,0.f,0.f,0.f}, acc3 = {0.f,0.f,0.f,0.f};
        f32x4 acc4 = {0.f,0.f,0.f,0.f}, acc5 = {0.f,0.f,0.f,0.f};
        f32x4 acc6 = {0.f,0.f,0.f,0.f}, acc7 = {0.f,0.f,0.f,0.f};

        MKLDS8(0, 0)                     // kt=0: all 8 from LDS
        MKLDS8(1, 8)                     // kt=1: all 8 from LDS
        {                                // kt=2: nl0..2 LDS, nl3..7 streamed
            f16x8 av = *(const f16x8*)&hp[64 + 8 * gg];
            { f16x8 bv = sm.bl[w][16][lane]; MMV(0, bv) }
            { f16x8 bv = sm.bl[w][17][lane]; MMV(1, bv) }
            { f16x8 bv = sm.bl[w][18][lane]; MMV(2, bv) }
            MMS(2,3) MMS(2,4) MMS(2,5) MMS(2,6) MMS(2,7)
        }
        MKSTRM(3) MKSTRM(4) MKSTRM(5) MKSTRM(6) MKSTRM(7)

        // ---- wave-local gates: unit u's 4 gates are acc(2q+sel)[0] ----
        if (lane < 32) {
            float zi = (sel ? acc1[0] : acc0[0]) + xq0;
            float zf = (sel ? acc3[0] : acc2[0]) + xq1;
            float zg = (sel ? acc5[0] : acc4[0]) + xq2;
            float zo = (sel ? acc7[0] : acc6[0]) + xq3;
            float ig = sigmoidf_(zi);
            float fg = sigmoidf_(zf);
            float gv = fmaxf(zg, 0.f);
            float og = sigmoidf_(zo);
            c_state = fg * c_state + ig * gv;
            float h = og * fmaxf(c_state, 0.f);
            sm.h16[nxt][u] = (_Float16)h;
            sm.pd[cur][u]  = h * dwr;
        }
        __syncthreads();                 // the ONE barrier: h[nxt], pd[cur] sealed
    }

    // ---- epilogue: out[T-1] ----
    if (tau < 64) {
        const float* pp = sm.pd[(T_ - 1) & 1];
        float s = pp[tau] + pp[tau + 64] + pp[tau + 128] + pp[tau + 192];
        #pragma unroll
        for (int off = 32; off > 0; off >>= 1)
            s += __shfl_down(s, off);
        if (tau == 0) out[(size_t)b * T_ + (T_ - 1)] = s + db0;
    }
}

// ---------------------------------------------------------------------------
// Kernel 2 (secondary, r15-proven): used when ws lacks the +512 KiB slack.
// ---------------------------------------------------------------------------
struct Smem15 {
    _Float16 h16[256];
    float    z[G4];
    float    pd[U_];
    f16x8    bl[8][17][64];
};

#define FOR_AG(X) \
    X(2,1) X(2,2) X(2,3) X(2,4) X(2,5) X(2,6) X(2,7) \
    X(3,0) X(3,1) X(3,2) X(3,3) X(3,4) X(3,5) X(3,6) X(3,7) \
    X(4,0) X(4,1) X(4,2) X(4,3) X(4,4) X(4,5) X(4,6) X(4,7) \
    X(5,0) X(5,1) X(5,2) X(5,3) X(5,4) X(5,5) X(5,6) X(5,7) \
    X(6,0) X(6,1) X(6,2) X(6,3) X(6,4) X(6,5) X(6,6) X(6,7) \
    X(7,0) X(7,1) X(7,2) X(7,3) X(7,4) X(7,5) X(7,6) X(7,7)

#define DB(K,N) f16x8 bF_##K##_##N;
#define IB(K,N) bF_##K##_##N = load_bfrag(Um, w8 + (N), (K), gg, li);
#define MMR(K, N)  acc##N = __builtin_amdgcn_mfma_f32_16x16x32_f16(av, bF_##K##_##N, acc##N, 0, 0, 0);
#define MKLDS15(KT, FB) { \
    f16x8 av = *(const f16x8*)&sm.h16[32 * (KT) + 8 * gg]; \
    { f16x8 bv = sm.bl[w][(FB)+0][lane]; MMV(0, bv) } \
    { f16x8 bv = sm.bl[w][(FB)+1][lane]; MMV(1, bv) } \
    { f16x8 bv = sm.bl[w][(FB)+2][lane]; MMV(2, bv) } \
    { f16x8 bv = sm.bl[w][(FB)+3][lane]; MMV(3, bv) } \
    { f16x8 bv = sm.bl[w][(FB)+4][lane]; MMV(4, bv) } \
    { f16x8 bv = sm.bl[w][(FB)+5][lane]; MMV(5, bv) } \
    { f16x8 bv = sm.bl[w][(FB)+6][lane]; MMV(6, bv) } \
    { f16x8 bv = sm.bl[w][(FB)+7][lane]; MMV(7, bv) } }
#define MKREG(KT) { \
    f16x8 av = *(const f16x8*)&sm.h16[32 * (KT) + 8 * gg]; \
    MMR(KT,0) MMR(KT,1) MMR(KT,2) MMR(KT,3) \
    MMR(KT,4) MMR(KT,5) MMR(KT,6) MMR(KT,7) }

__global__
__attribute__((amdgpu_flat_work_group_size(512, 512), amdgpu_waves_per_eu(2, 2)))
void lstm_kernel_r15(
        const float* __restrict__ Um,
        const float* __restrict__ dw,
        const float* __restrict__ dbp,
        const float* __restrict__ xz,
        float* __restrict__ out) {
    __shared__ Smem15 sm;

    const int tau  = threadIdx.x;
    const int b    = blockIdx.x;
    const int w    = tau >> 6;
    const int lane = tau & 63;
    const int gg   = (tau >> 4) & 3;
    const int li   = tau & 15;
    const int w8   = 8 * w;

    FOR_AG(DB)
    FOR_AG(IB)
    __builtin_amdgcn_sched_barrier(0);

    #pragma unroll
    for (int f = 0; f < 17; ++f) {
        const int kt = f >> 3, nt = f & 7;
        sm.bl[w][f][lane] = load_bfrag(Um, w8 + nt, kt, gg, li);
    }

    if (tau < U_) sm.h16[tau] = (_Float16)0.f;

    const float dwr = (tau < U_) ? dw[tau] : 0.f;
    const float db0 = dbp[0];
    float c_state = 0.f;

    float xq0 = 0.f, xq1 = 0.f, xq2 = 0.f, xq3 = 0.f;
    if (tau < U_) {
        const float* xp = xz + (size_t)b * G4;
        xq0 = xp[tau]; xq1 = xp[U_ + tau]; xq2 = xp[2 * U_ + tau]; xq3 = xp[3 * U_ + tau];
    }
    __syncthreads();

    for (int t = 0; t < T_; ++t) {
        const int tn = (t + 1 < T_) ? t + 1 : t;
        float xn0 = 0.f, xn1 = 0.f, xn2 = 0.f, xn3 = 0.f;
        if (tau < U_) {
            const float* xp = xz + ((size_t)tn * B_ + b) * G4;
            xn0 = xp[tau]; xn1 = xp[U_ + tau]; xn2 = xp[2 * U_ + tau]; xn3 = xp[3 * U_ + tau];
        }
        __builtin_amdgcn_sched_barrier(0);

        f32x4 acc0 = {0.f,0.f,0.f,0.f}, acc1 = {0.f,0.f,0.f,0.f};
        f32x4 acc2 = {0.f,0.f,0.f,0.f}, acc3 = {0.f,0.f,0.f,0.f};
        f32x4 acc4 = {0.f,0.f,0.f,0.f}, acc5 = {0.f,0.f,0.f,0.f};
        f32x4 acc6 = {0.f,0.f,0.f,0.f}, acc7 = {0.f,0.f,0.f,0.f};

        MKLDS15(0, 0)
        MKLDS15(1, 8)
        {
            f16x8 av = *(const f16x8*)&sm.h16[64 + 8 * gg];
            { f16x8 bv = sm.bl[w][16][lane]; MMV(0, bv) }
            MMR(2,1) MMR(2,2) MMR(2,3) MMR(2,4) MMR(2,5) MMR(2,6) MMR(2,7)
        }
        MKREG(3) MKREG(4) MKREG(5) MKREG(6) MKREG(7)

        if (lane < 16) {
            const int zb = 128 * w + lane;
            sm.z[zb]       = acc0.x;  sm.z[zb + 16]  = acc1.x;
            sm.z[zb + 32]  = acc2.x;  sm.z[zb + 48]  = acc3.x;
            sm.z[zb + 64]  = acc4.x;  sm.z[zb + 80]  = acc5.x;
            sm.z[zb + 96]  = acc6.x;  sm.z[zb + 112] = acc7.x;
        }
        __syncthreads();

        if (tau < U_) {
            float zi = sm.z[tau]            + xq0;
            float zf = sm.z[U_ + tau]       + xq1;
            float zg = sm.z[2 * U_ + tau]   + xq2;
            float zo = sm.z[3 * U_ + tau]   + xq3;
            float ig = sigmoidf_(zi);
            float fg = sigmoidf_(zf);
            float gv = fmaxf(zg, 0.f);
            float og = sigmoidf_(zo);
            c_state = fg * c_state + ig * gv;
            float h = og * fmaxf(c_state, 0.f);
            sm.h16[tau] = (_Float16)h;
            sm.pd[tau]  = h * dwr;
        }
        __syncthreads();

        if (tau < 64) {
            float s = sm.pd[tau] + sm.pd[tau + 64] + sm.pd[tau + 128] + sm.pd[tau + 192];
            #pragma unroll
            for (int off = 32; off > 0; off >>= 1)
                s += __shfl_down(s, off);
            if (tau == 0) out[(size_t)b * T_ + t] = s + db0;
        }

        xq0 = xn0; xq1 = xn1; xq2 = xn2; xq3 = xn3;
    }
}

// ---------------------------------------------------------------------------
// Fallback (no workspace): streaming kernel, correctness only.
// ---------------------------------------------------------------------------
__global__ __launch_bounds__(1024) void lstm_fallback(
        const float* __restrict__ x,  const float* __restrict__ W,
        const float* __restrict__ Um, const float* __restrict__ bias,
        const float* __restrict__ dw, const float* __restrict__ dbp,
        float* __restrict__ out) {
    __shared__ float h_s[U_];
    __shared__ float z_s2[G4];
    __shared__ float pd_s2[U_];
    const int g = threadIdx.x;
    const int b = blockIdx.x;
    const float bg  = bias[g];
    const float dwr = (g < U_) ? dw[g] : 0.f;
    const float db0 = dbp[0];
    float c = 0.f;
    if (g < U_) h_s[g] = 0.f;
    __syncthreads();
    const float* Ucol = Um + g;
    for (int t = 0; t < T_; ++t) {
        float acc = bg;
        const float* xrow = x + ((size_t)b * T_ + t) * D_;
        for (int d = 0; d < D_; ++d) acc += xrow[d] * W[(size_t)d * G4 + g];
        for (int k = 0; k < U_; ++k) acc += h_s[k] * Ucol[(size_t)k * G4];
        z_s2[g] = acc;
        __syncthreads();
        if (g < U_) {
            float ig = sigmoidf_(z_s2[g]);
            float fg = sigmoidf_(z_s2[U_ + g]);
            float gg2 = fmaxf(z_s2[2 * U_ + g], 0.f);
            float og = sigmoidf_(z_s2[3 * U_ + g]);
            c = fg * c + ig * gg2;
            float h = og * fmaxf(c, 0.f);
            h_s[g] = h; pd_s2[g] = h * dwr;
        }
        __syncthreads();
        if (g < 64) {
            float s = pd_s2[g] + pd_s2[g + 64] + pd_s2[g + 128] + pd_s2[g + 192];
            #pragma unroll
            for (int off = 32; off > 0; off >>= 1) s += __shfl_down(s, off);
            if (g == 0) out[(size_t)b * T_ + t] = s + db0;
        }
        __syncthreads();
    }
}

// ---------------------------------------------------------------------------
extern "C" void kernel_launch(void* const* d_in, const int* in_sizes, int n_in,
                              void* d_out, int out_size, void* d_ws, size_t ws_size,
                              hipStream_t stream) {
    const float* x    = (const float*)d_in[0];
    const float* W    = (const float*)d_in[1];
    const float* Um   = (const float*)d_in[2];
    const float* bias = (const float*)d_in[3];
    const float* dw   = (const float*)d_in[4];
    const float* db   = (const float*)d_in[5];
    float* out = (float*)d_out;

    const size_t need_xz  = (size_t)T_ * B_ * G4 * sizeof(float);   // 128 MiB
    const size_t pk_bytes = (size_t)512 * 64 * 16;                  // 512 KiB

    if (ws_size >= need_xz + pk_bytes) {
        f16x8* pk = (f16x8*)d_ws;
        float* xz = (float*)((char*)d_ws + pk_bytes);
        dim3 gridX(G4 / 256, (T_ * B_) / 16);
        xz_kernel<<<gridX, 256, 0, stream>>>(x, W, bias, xz);
        pack_kernel<<<128, 256, 0, stream>>>(Um, pk);
        lstm_kernel<<<B_, NT, 0, stream>>>(Um, dw, db, xz, pk, out);
    } else if (ws_size >= need_xz) {
        float* xz = (float*)d_ws;
        dim3 gridX(G4 / 256, (T_ * B_) / 16);
        xz_kernel<<<gridX, 256, 0, stream>>>(x, W, bias, xz);
        lstm_kernel_r15<<<B_, 512, 0, stream>>>(Um, dw, db, xz, out);
    } else {
        lstm_fallback<<<B_, 1024, 0, stream>>>(x, W, Um, bias, dw, db, out);
    }
}